// Round 9
// baseline (280.250 us; speedup 1.0000x reference)
//
#include <hip/hip_runtime.h>
#include <math.h>

#define N_NODES 50000
#define N_EDGES 1600000
#define F 256
#define ALPHA 0.2f
#define NP 50048   // padded node count (multiple of 128)
#define NB 392     // coarse buckets: bucket = row >> 7 (128 rows each)
#define CAP 5632   // fixed bucket capacity (Poisson mean 4096, sigma 64 -> 24σ)
#define EPB 4096   // edges per binning block
#define NAB ((N_EDGES + EPB - 1) / EPB)  // 391
#define GEMM_BLOCKS 782  // (NP/128) * (F/128)
#define XC_BLOCKS 2048   // x->bf16 conversion blocks (in prep_w grid)
#define PULL_BLOCKS 2048 // persistent pull blocks (8 per CU)
#define NW_TOT (PULL_BLOCKS * 4)  // 8192 persistent waves
#define NPW 7    // nodes per wave (ceil(50000/8192))
#define NBIN 8   // col bins (col >> 13), 3.2 MB Wh slice per bin

typedef short bf16x8 __attribute__((ext_vector_type(8)));
typedef short bf16x4 __attribute__((ext_vector_type(4)));
typedef float f32x4 __attribute__((ext_vector_type(4)));
typedef _Float16 half4 __attribute__((ext_vector_type(4)));
typedef _Float16 half8 __attribute__((ext_vector_type(8)));

__device__ __forceinline__ unsigned short f2bf(float f) {
  union { float f; unsigned u; } v; v.f = f;
  unsigned u = v.u;
  return (unsigned short)((u + 0x7fffu + ((u >> 16) & 1u)) >> 16);
}

__device__ __forceinline__ unsigned short f2h_bits(float f) {
  union { _Float16 h; unsigned short u; } v;
  v.h = (_Float16)f;
  return v.u;
}

__device__ __forceinline__ float h_bits2f(unsigned short u) {
  union { _Float16 h; unsigned short u; } v;
  v.u = u;
  return (float)v.h;
}

// ---- L1: prep_w:
//  blocks 0-63   : transpose W -> Wt bf16
//  block  64     : zero gcur; cb = a_b
//  blocks 65-113 : zero f_dst / f_row
//  blocks 114+   : convert x (f32) -> xb (bf16), pad rows zeroed.
__global__ __launch_bounds__(256) void prep_w(const float* __restrict__ W,
                                              const float* __restrict__ x,
                                              const float* __restrict__ a_b,
                                              unsigned short* __restrict__ Wt,
                                              unsigned short* __restrict__ xb,
                                              float* __restrict__ f_dst,
                                              float* __restrict__ f_row,
                                              float* __restrict__ cb,
                                              int* __restrict__ gcur) {
  if (blockIdx.x == 64) {  // zero the bucket cursors
    for (int i = threadIdx.x; i < NB; i += 256) gcur[i] = 0;
    if (threadIdx.x == 0) cb[0] = a_b[0];
    return;
  }
  if (blockIdx.x > 64 && blockIdx.x < 114) {  // zero f_dst / f_row
    int idx = (blockIdx.x - 65) * 256 + threadIdx.x;
    if (idx < NP / 4) {
      ((float4*)f_dst)[idx] = make_float4(0.f, 0.f, 0.f, 0.f);
      ((float4*)f_row)[idx] = make_float4(0.f, 0.f, 0.f, 0.f);
    }
    return;
  }
  const int lane = threadIdx.x & 63, w = threadIdx.x >> 6;
  if (blockIdx.x >= 114) {  // xcvt: grid-stride fat blocks, 4 rows/iter
    const int slot = blockIdx.x - 114;
    for (int node = slot * 4 + w; node < NP; node += XC_BLOCKS * 4) {
      bf16x4 v;
      if (node < N_NODES) {
        float4 xv = *(const float4*)(x + (size_t)node * F + lane * 4);
        v[0] = (short)f2bf(xv.x); v[1] = (short)f2bf(xv.y);
        v[2] = (short)f2bf(xv.z); v[3] = (short)f2bf(xv.w);
      } else {
        v[0] = 0; v[1] = 0; v[2] = 0; v[3] = 0;
      }
      *(bf16x4*)(xb + (size_t)node * F + lane * 4) = v;
    }
    return;
  }
  const int k = blockIdx.x * 4 + w;  // 0..255
  float4 wv = *(const float4*)(W + (size_t)k * F + lane * 4);
  Wt[(size_t)(lane * 4 + 0) * F + k] = f2bf(wv.x);
  Wt[(size_t)(lane * 4 + 1) * F + k] = f2bf(wv.y);
  Wt[(size_t)(lane * 4 + 2) * F + k] = f2bf(wv.z);
  Wt[(size_t)(lane * 4 + 3) * F + k] = f2bf(wv.w);
}

// ---- L2: fused GEMM [0,782) + binA2 [782,1173)
#define LDSK 72
__global__ __launch_bounds__(256) void gemm_fvec_binA2(
    const unsigned short* __restrict__ xb,
    const unsigned short* __restrict__ Wt,
    const float* __restrict__ bias,
    const float* __restrict__ aw,
    const int* __restrict__ row,
    const int* __restrict__ col,
    _Float16* __restrict__ Wh,
    float* __restrict__ f_dst,
    float* __restrict__ f_row,
    int* __restrict__ gcur,
    unsigned* __restrict__ gstage) {
  __shared__ char smem[2 * 128 * LDSK * 2];  // 36864 B arena
  if (blockIdx.x < GEMM_BLOCKS) {
    // ---- GEMM part: Wh(fp16) = xb(bf16) @ Wt^T + bias, with fused
    // f_dst/f_row = Wh @ a1 / Wh @ a2 epilogue (atomic per-row partials).
    // Staging is now pure bf16x8 copies (xb pre-converted in prep_w).
    short* As = (short*)smem;
    short* Bs = As + 128 * LDSK;
    const int tid = threadIdx.x;
    const int lane = tid & 63;
    const int w = tid >> 6;
    const int wm = w >> 1, wn = w & 1;
    const int m0 = (blockIdx.x >> 1) * 128;
    const int n0 = (blockIdx.x & 1) * 128;
    f32x4 acc[4][4] = {{{0.f, 0.f, 0.f, 0.f}}};
    const int srow = tid >> 3;   // 0..31
    const int schunk = tid & 7;  // 0..7
    for (int k0 = 0; k0 < F; k0 += 64) {
#pragma unroll
      for (int i = 0; i < 4; ++i) {
        int r = i * 32 + srow;
        *(bf16x8*)&As[r * LDSK + schunk * 8] =
            *(const bf16x8*)(xb + (size_t)(m0 + r) * F + k0 + schunk * 8);
        *(bf16x8*)&Bs[r * LDSK + schunk * 8] =
            *(const bf16x8*)(Wt + (size_t)(n0 + r) * F + k0 + schunk * 8);
      }
      __syncthreads();
#pragma unroll
      for (int kk = 0; kk < 64; kk += 32) {
        const int rowsel = lane & 15;
        const int ksel = kk + (lane >> 4) * 8;
        bf16x8 af[4], bfr[4];
#pragma unroll
        for (int t = 0; t < 4; ++t) {
          af[t] = *(bf16x8*)&As[(wm * 64 + t * 16 + rowsel) * LDSK + ksel];
          bfr[t] = *(bf16x8*)&Bs[(wn * 64 + t * 16 + rowsel) * LDSK + ksel];
        }
#pragma unroll
        for (int mi = 0; mi < 4; ++mi)
#pragma unroll
          for (int nj = 0; nj < 4; ++nj)
            acc[mi][nj] = __builtin_amdgcn_mfma_f32_16x16x32_bf16(
                af[mi], bfr[nj], acc[mi][nj], 0, 0, 0);
      }
      __syncthreads();
    }
    const int crow = (lane >> 4) * 4;
    const int ccol = lane & 15;
    float s1[16], s2[16];
#pragma unroll
    for (int t = 0; t < 16; ++t) { s1[t] = 0.f; s2[t] = 0.f; }
#pragma unroll
    for (int nj = 0; nj < 4; ++nj) {
      int gc = n0 + wn * 64 + nj * 16 + ccol;
      float bv = bias[gc];
      float a1v = aw[gc];
      float a2v = aw[F + gc];
#pragma unroll
      for (int mi = 0; mi < 4; ++mi) {
        int gr = m0 + wm * 64 + mi * 16 + crow;
#pragma unroll
        for (int r = 0; r < 4; ++r) {
          float wh = acc[mi][nj][r] + bv;
          Wh[(size_t)(gr + r) * F + gc] = (_Float16)wh;
          s1[mi * 4 + r] += wh * a1v;
          s2[mi * 4 + r] += wh * a2v;
        }
      }
    }
    // reduce the 64-col partial over the 16 ccol lanes of each row group
#pragma unroll
    for (int t = 0; t < 16; ++t) {
#pragma unroll
      for (int off = 8; off > 0; off >>= 1) {
        s1[t] += __shfl_xor(s1[t], off, 64);
        s2[t] += __shfl_xor(s2[t], off, 64);
      }
    }
    if (ccol == 0) {
#pragma unroll
      for (int mi = 0; mi < 4; ++mi)
#pragma unroll
        for (int r = 0; r < 4; ++r) {
          int gr = m0 + wm * 64 + mi * 16 + crow + r;
          atomicAdd(&f_dst[gr], s1[mi * 4 + r]);
          atomicAdd(&f_row[gr], s2[mi * 4 + r]);
        }
    }
    return;
  }
  // ---- binA2 part: pack = b(9b) | lr(7b) | col(16b)
  {
    int* h = (int*)smem;
    int* lofs = h + NB;
    int* lcur = lofs + NB;
    int* gb = lcur + NB;
    unsigned* stage = (unsigned*)(gb + NB);  // EPB entries
    const int t = threadIdx.x;
    for (int i = t; i < NB; i += 256) { h[i] = 0; lcur[i] = 0; }
    __syncthreads();
    const int base = (blockIdx.x - GEMM_BLOCKS) * EPB;
    const int cnt = min(EPB, N_EDGES - base);
#pragma unroll
    for (int j = 0; j < 16; ++j) {
      int k = base + j * 256 + t;
      if (k < N_EDGES) atomicAdd(&h[row[k] >> 7], 1);
    }
    __syncthreads();
    if (t == 0) {
      int run = 0;
      for (int i = 0; i < NB; ++i) { lofs[i] = run; run += h[i]; }
    }
    __syncthreads();
    for (int i = t; i < NB; i += 256)
      if (h[i] > 0) gb[i] = atomicAdd(&gcur[i], h[i]);
    __syncthreads();
#pragma unroll
    for (int j = 0; j < 16; ++j) {
      int k = base + j * 256 + t;
      if (k < N_EDGES) {
        int r = row[k], b = r >> 7;
        int lp = lofs[b] + atomicAdd(&lcur[b], 1);
        stage[lp] = ((unsigned)b << 23) | ((unsigned)(r & 127) << 16) |
                    (unsigned)col[k];
      }
    }
    __syncthreads();
#pragma unroll
    for (int j = 0; j < 16; ++j) {
      int s = j * 256 + t;
      if (s < cnt) {
        unsigned wv = stage[s];
        int b = wv >> 23;
        gstage[(size_t)b * CAP + gb[b] + (s - lofs[b])] = wv & 0x007FFFFFu;
      }
    }
  }
}

// ---- L3: binB (512 thr, 392 blocks of 128 rows): per-(row,colbin)
// histogram -> entries COL-SORTED within each row (8 bins, q = col>>13);
// exports per-(row,bin) absolute start offsets (bstart) for the pull sweep.
__global__ __launch_bounds__(512) void binB(const int* __restrict__ gcur,
                                            const unsigned* __restrict__ gstage,
                                            const float* __restrict__ f_dst,
                                            const float* __restrict__ f_row,
                                            const float* __restrict__ cb,
                                            int2* __restrict__ rsc,
                                            float* __restrict__ inv_denom,
                                            unsigned* __restrict__ csr,
                                            int* __restrict__ bstart) {
  __shared__ int cnt2[1024];  // per (row, colbin)
  __shared__ int cur2[1024];
  __shared__ int rcnt[128], rbase[128];
  __shared__ float dsum[128];
  const int t = threadIdx.x;
  const int b = blockIdx.x;
  for (int i = t; i < 1024; i += 512) cnt2[i] = 0;
  if (t < 128) dsum[t] = 0.f;
  __syncthreads();
  const int nb = gcur[b];
  const int start = b * CAP;
  const float cbs = cb[0];
  for (int s = t; s < nb; s += 512) {
    unsigned wv = gstage[start + s];
    int key = (((wv >> 16) & 127) << 3) | ((wv & 0xFFFFu) >> 13);
    atomicAdd(&cnt2[key], 1);
  }
  __syncthreads();
  if (t < 128) {
    int tot = 0;
#pragma unroll
    for (int q = 0; q < 8; ++q) tot += cnt2[t * 8 + q];
    rcnt[t] = tot;
  }
  __syncthreads();
  if (t == 0) {
    int run = 0;
    for (int i = 0; i < 128; ++i) { rbase[i] = run; run += rcnt[i]; }
  }
  __syncthreads();
  if (t < 128) {
    int base = start + rbase[t];
    int g = (b << 7) + t;
    if (g < N_NODES) rsc[g] = make_int2(base, rcnt[t]);
    int run = base;
    int bs[8];
#pragma unroll
    for (int q = 0; q < 8; ++q) {
      cur2[t * 8 + q] = run;
      bs[q] = run;
      run += cnt2[t * 8 + q];
    }
    if (g < N_NODES) {
      *(int4*)&bstart[(size_t)g * 8]     = make_int4(bs[0], bs[1], bs[2], bs[3]);
      *(int4*)&bstart[(size_t)g * 8 + 4] = make_int4(bs[4], bs[5], bs[6], bs[7]);
    }
  }
  __syncthreads();
  for (int s = t; s < nb; s += 512) {
    unsigned wv = gstage[start + s];
    int lr = (wv >> 16) & 127;
    int c = wv & 0xFFFF;
    float ev = f_dst[c] + f_row[(b << 7) + lr] + cbs;
    ev = ev > 0.f ? ev : ALPHA * ev;
    float ex = __expf(ev);
    int p = atomicAdd(&cur2[(lr << 3) | (c >> 13)], 1);  // absolute index
    csr[p] = ((unsigned)f2h_bits(ex) << 16) | (unsigned)c;
    atomicAdd(&dsum[lr], ex);
  }
  __syncthreads();
  if (t < 128) {
    int g = (b << 7) + t;
    if (g < N_NODES) inv_denom[g] = (rcnt[t] > 0) ? (1.0f / dsum[t]) : 0.f;
  }
}

// ---- L4: pull (EXACT round-5 structure, best measured: 96.5 us).
// Phase-synchronized col-bin sweep + 4-deep MLP batches.
__global__ __launch_bounds__(256) void gat_pull(const int2* __restrict__ rsc,
                                                const unsigned* __restrict__ csr,
                                                const float* __restrict__ inv_denom,
                                                const int* __restrict__ bstart,
                                                const _Float16* __restrict__ Wh,
                                                float* __restrict__ out) {
  __shared__ int sb[4 * NPW * 9];  // 4 waves x 7 nodes x (8 starts + row end)
  const int lane = threadIdx.x & 63;
  const int wv_id = threadIdx.x >> 6;
  const int wid = blockIdx.x * 4 + wv_id;
  // cooperative bounds stage: entry e = w*63 + jn*9 + q
  for (int e = threadIdx.x; e < 4 * NPW * 9; e += 256) {
    int w = e / (NPW * 9);
    int rem = e - w * (NPW * 9);
    int jn = rem / 9, q = rem - jn * 9;
    int i = blockIdx.x * 4 + w + jn * NW_TOT;
    int v = 0;
    if (i < N_NODES) {
      if (q < 8) v = bstart[(size_t)i * 8 + q];
      else { int2 rc = rsc[i]; v = rc.x + rc.y; }
    }
    sb[e] = v;
  }
  __syncthreads();
  const int* mb = &sb[wv_id * NPW * 9];
  const char* whb = (const char*)Wh;
  const unsigned chanoff = (unsigned)lane * 8u;  // 4 fp16 channels / lane
  const int l16 = lane & 15;
  float a0[NPW], a1[NPW], a2[NPW], a3[NPW];
#pragma unroll
  for (int jn = 0; jn < NPW; ++jn) a0[jn] = a1[jn] = a2[jn] = a3[jn] = 0.f;
  for (int q = 0; q < NBIN; ++q) {
    // prefetch jn=0 segment csr line
    int pp = mb[q], pe = mb[q + 1];
    unsigned cw0 = 0;
    if (pp + l16 < pe) cw0 = csr[pp + l16];
#pragma unroll
    for (int jn = 0; jn < NPW; ++jn) {
      const int cpp = pp, cpe = pe;
      unsigned cw = cw0;
      if (jn + 1 < NPW) {  // prefetch next node's segment
        pp = mb[(jn + 1) * 9 + q];
        pe = mb[(jn + 1) * 9 + q + 1];
        cw0 = 0;
        if (pp + l16 < pe) cw0 = csr[pp + l16];
      }
      const int len = cpe - cpp;
      for (int done = 0; done < len; done += 16) {
        if (done) {  // chunks beyond the first: reload line (rare, len>16)
          cw = 0;
          if (cpp + done + l16 < cpe) cw = csr[cpp + done + l16];
        }
        int cl = len - done;
        if (cl > 16) cl = 16;
        for (int jb = 0; jb < cl; jb += 4) {
          // 4-edge batch: uniform extracts, clamped to edge 0 when past end
          const int j1 = (jb + 1 < cl) ? jb + 1 : 0;
          const int j2 = (jb + 2 < cl) ? jb + 2 : 0;
          const int j3 = (jb + 3 < cl) ? jb + 3 : 0;
          unsigned w0 = __builtin_amdgcn_readlane(cw, jb);
          unsigned w1 = __builtin_amdgcn_readlane(cw, j1);
          unsigned w2 = __builtin_amdgcn_readlane(cw, j2);
          unsigned w3 = __builtin_amdgcn_readlane(cw, j3);
          half4 v0 = *(const half4*)(whb + (size_t)(w0 & 0xFFFFu) * 512u + chanoff);
          half4 v1 = *(const half4*)(whb + (size_t)(w1 & 0xFFFFu) * 512u + chanoff);
          half4 v2 = *(const half4*)(whb + (size_t)(w2 & 0xFFFFu) * 512u + chanoff);
          half4 v3 = *(const half4*)(whb + (size_t)(w3 & 0xFFFFu) * 512u + chanoff);
          float x0 = h_bits2f((unsigned short)(w0 >> 16));
          float x1 = (jb + 1 < cl) ? h_bits2f((unsigned short)(w1 >> 16)) : 0.f;
          float x2 = (jb + 2 < cl) ? h_bits2f((unsigned short)(w2 >> 16)) : 0.f;
          float x3 = (jb + 3 < cl) ? h_bits2f((unsigned short)(w3 >> 16)) : 0.f;
          a0[jn] += x0 * (float)v0[0]; a1[jn] += x0 * (float)v0[1];
          a2[jn] += x0 * (float)v0[2]; a3[jn] += x0 * (float)v0[3];
          a0[jn] += x1 * (float)v1[0]; a1[jn] += x1 * (float)v1[1];
          a2[jn] += x1 * (float)v1[2]; a3[jn] += x1 * (float)v1[3];
          a0[jn] += x2 * (float)v2[0]; a1[jn] += x2 * (float)v2[1];
          a2[jn] += x2 * (float)v2[2]; a3[jn] += x2 * (float)v2[3];
          a0[jn] += x3 * (float)v3[0]; a1[jn] += x3 * (float)v3[1];
          a2[jn] += x3 * (float)v3[2]; a3[jn] += x3 * (float)v3[3];
        }
      }
    }
  }
  // finalize: scale, relu, store (lane owns its 4 channels directly)
#pragma unroll
  for (int jn = 0; jn < NPW; ++jn) {
    int i = wid + jn * NW_TOT;
    if (i >= N_NODES) continue;
    const float inv = inv_denom[i];
    float4 o = make_float4(fmaxf(a0[jn] * inv, 0.f), fmaxf(a1[jn] * inv, 0.f),
                           fmaxf(a2[jn] * inv, 0.f), fmaxf(a3[jn] * inv, 0.f));
    ((float4*)out)[(size_t)i * 64 + lane] = o;
  }
}

extern "C" void kernel_launch(void* const* d_in, const int* in_sizes, int n_in,
                              void* d_out, int out_size, void* d_ws, size_t ws_size,
                              hipStream_t stream) {
  const float* x   = (const float*)d_in[0];
  const float* W_w = (const float*)d_in[1];
  const float* W_b = (const float*)d_in[2];
  const float* a_w = (const float*)d_in[3];
  const float* a_b = (const float*)d_in[4];
  const int*   row = (const int*)d_in[5];
  const int*   col = (const int*)d_in[6];
  float* out = (float*)d_out;

  float* ws = (float*)d_ws;
  size_t off = 0;
  _Float16* Wh = (_Float16*)(ws + off); off += (size_t)NP * F / 2;       // fp16
  unsigned short* xb = (unsigned short*)(ws + off); off += (size_t)NP * F / 2;  // bf16
  unsigned short* Wt = (unsigned short*)(ws + off); off += (F * F) / 2;  // bf16
  float* cb = ws + off;            off += 8;
  float* f_dst = ws + off;         off += NP;
  float* f_row = ws + off;         off += NP;
  int* gcur = (int*)(ws + off);    off += NB;
  int2* rsc = (int2*)(ws + off);   off += 2 * (size_t)NP;
  float* inv_denom = (float*)(ws + off); off += NP;
  unsigned* gstage = (unsigned*)(ws + off); off += (size_t)NB * CAP;
  unsigned* csr = (unsigned*)(ws + off); off += (size_t)NB * CAP;
  int* bstart = (int*)(ws + off);  off += (size_t)NP * 8;
  (void)ws_size; (void)in_sizes; (void)n_in; (void)out_size;

  hipLaunchKernelGGL(prep_w, dim3(114 + XC_BLOCKS), dim3(256), 0, stream,
                     W_w, x, a_b, Wt, xb, f_dst, f_row, cb, gcur);
  hipLaunchKernelGGL(gemm_fvec_binA2, dim3(GEMM_BLOCKS + NAB),
                     dim3(256), 0, stream, xb, Wt, W_b, a_w, row, col, Wh,
                     f_dst, f_row, gcur, gstage);
  hipLaunchKernelGGL(binB, dim3(NB), dim3(512), 0, stream, gcur, gstage,
                     f_dst, f_row, cb, rsc, inv_denom, csr, bstart);
  hipLaunchKernelGGL(gat_pull, dim3(PULL_BLOCKS), dim3(256), 0, stream,
                     rsc, csr, inv_denom, bstart, Wh, out);
}

// Round 10
// 265.680 us; speedup vs baseline: 1.0548x; 1.0548x over previous
//
#include <hip/hip_runtime.h>
#include <math.h>

#define N_NODES 50000
#define N_EDGES 1600000
#define F 256
#define ALPHA 0.2f
#define NP 50048   // padded node count (multiple of 128)
#define NB 196     // coarse buckets: bucket = row >> 8 (256 rows each)
#define CAP 10240  // fixed bucket capacity (Poisson mean 8192, sigma 91 -> 22σ)
#define EPB 4096   // edges per binning block
#define NAB ((N_EDGES + EPB - 1) / EPB)  // 391
#define GEMM_BLOCKS 782  // (NP/128) * (F/128)
#define FVEC_SLOTS 2048  // grid-stride fat blocks for the projection part
#define PULL_BLOCKS 2048 // persistent pull blocks (8 per CU)
#define NW_TOT (PULL_BLOCKS * 4)  // 8192 persistent waves
#define NPW 7    // nodes per wave (ceil(50000/8192))
#define NBIN 8   // col bins (col >> 13), 3.2 MB Wh slice per bin

typedef short bf16x8 __attribute__((ext_vector_type(8)));
typedef float f32x4 __attribute__((ext_vector_type(4)));
typedef _Float16 half4 __attribute__((ext_vector_type(4)));
typedef _Float16 half8 __attribute__((ext_vector_type(8)));

__device__ __forceinline__ unsigned short f2bf(float f) {
  union { float f; unsigned u; } v; v.f = f;
  unsigned u = v.u;
  return (unsigned short)((u + 0x7fffu + ((u >> 16) & 1u)) >> 16);
}

__device__ __forceinline__ unsigned short f2h_bits(float f) {
  union { _Float16 h; unsigned short u; } v;
  v.h = (_Float16)f;
  return v.u;
}

__device__ __forceinline__ float h_bits2f(unsigned short u) {
  union { _Float16 h; unsigned short u; } v;
  v.u = u;
  return (float)v.h;
}

// ---- L1: prep_w: W -> Wt bf16 transposed; wa = W @ a_halves; cb; zero gcur
__global__ __launch_bounds__(256) void prep_w(const float* __restrict__ W,
                                              const float* __restrict__ a_w,
                                              const float* __restrict__ W_b,
                                              const float* __restrict__ a_b,
                                              unsigned short* __restrict__ Wt,
                                              float* __restrict__ wa,
                                              float* __restrict__ cb,
                                              int* __restrict__ gcur) {
  if (blockIdx.x == 64) {  // zero the bucket cursors (replaces memset launch)
    if (threadIdx.x < NB) gcur[threadIdx.x] = 0;
    return;
  }
  const int lane = threadIdx.x & 63, w = threadIdx.x >> 6;
  const int k = blockIdx.x * 4 + w;  // 0..255
  float4 wv = *(const float4*)(W + (size_t)k * F + lane * 4);
  float4 a1 = *(const float4*)(a_w + lane * 4);
  float4 a2 = *(const float4*)(a_w + F + lane * 4);
  Wt[(size_t)(lane * 4 + 0) * F + k] = f2bf(wv.x);
  Wt[(size_t)(lane * 4 + 1) * F + k] = f2bf(wv.y);
  Wt[(size_t)(lane * 4 + 2) * F + k] = f2bf(wv.z);
  Wt[(size_t)(lane * 4 + 3) * F + k] = f2bf(wv.w);
  float s1 = wv.x * a1.x + wv.y * a1.y + wv.z * a1.z + wv.w * a1.w;
  float s2 = wv.x * a2.x + wv.y * a2.y + wv.z * a2.z + wv.w * a2.w;
#pragma unroll
  for (int off = 32; off > 0; off >>= 1) {
    s1 += __shfl_down(s1, off, 64);
    s2 += __shfl_down(s2, off, 64);
  }
  if (lane == 0) { wa[k] = s1; wa[F + k] = s2; }
  if (blockIdx.x == 0 && w == 0) {
    float4 b = *(const float4*)(W_b + lane * 4);
    float t1 = b.x * (a1.x + a2.x) + b.y * (a1.y + a2.y) +
               b.z * (a1.z + a2.z) + b.w * (a1.w + a2.w);
#pragma unroll
    for (int off = 32; off > 0; off >>= 1) t1 += __shfl_down(t1, off, 64);
    if (lane == 0) cb[0] = t1 + a_b[0];
  }
}

// ---- L2: fused GEMM [0,782) + binA2 [782,1173) + fvec [1173,1173+2048)
#define LDSK 72
__global__ __launch_bounds__(256) void gemm_fvec_binA2(
    const float* __restrict__ x,
    const unsigned short* __restrict__ Wt,
    const float* __restrict__ bias,
    const float* __restrict__ wa,
    const int* __restrict__ row,
    const int* __restrict__ col,
    _Float16* __restrict__ Wh,
    float* __restrict__ f_dst,
    float* __restrict__ f_row,
    int* __restrict__ gcur,
    unsigned* __restrict__ gstage) {
  __shared__ char smem[2 * 128 * LDSK * 2];  // 36864 B arena
  if (blockIdx.x < GEMM_BLOCKS) {
    // ---- GEMM part: Wh(fp16) = bf16(x) @ Wt^T + bias
    short* As = (short*)smem;
    short* Bs = As + 128 * LDSK;
    const int tid = threadIdx.x;
    const int lane = tid & 63;
    const int w = tid >> 6;
    const int wm = w >> 1, wn = w & 1;
    const int m0 = (blockIdx.x >> 1) * 128;
    const int n0 = (blockIdx.x & 1) * 128;
    f32x4 acc[4][4] = {{{0.f, 0.f, 0.f, 0.f}}};
    const int srow = tid >> 3;   // 0..31
    const int schunk = tid & 7;  // 0..7
    for (int k0 = 0; k0 < F; k0 += 64) {
#pragma unroll
      for (int i = 0; i < 4; ++i) {
        int r = i * 32 + srow;
        int gm = m0 + r; if (gm > N_NODES - 1) gm = N_NODES - 1;
        const float* src = x + (size_t)gm * F + k0 + schunk * 8;
        float4 lo = *(const float4*)src;
        float4 hi = *(const float4*)(src + 4);
        bf16x8 v;
        v[0] = (short)f2bf(lo.x); v[1] = (short)f2bf(lo.y);
        v[2] = (short)f2bf(lo.z); v[3] = (short)f2bf(lo.w);
        v[4] = (short)f2bf(hi.x); v[5] = (short)f2bf(hi.y);
        v[6] = (short)f2bf(hi.z); v[7] = (short)f2bf(hi.w);
        *(bf16x8*)&As[r * LDSK + schunk * 8] = v;
        *(bf16x8*)&Bs[r * LDSK + schunk * 8] =
            *(const bf16x8*)(Wt + (size_t)(n0 + r) * F + k0 + schunk * 8);
      }
      __syncthreads();
#pragma unroll
      for (int kk = 0; kk < 64; kk += 32) {
        const int rowsel = lane & 15;
        const int ksel = kk + (lane >> 4) * 8;
        bf16x8 af[4], bfr[4];
#pragma unroll
        for (int t = 0; t < 4; ++t) {
          af[t] = *(bf16x8*)&As[(wm * 64 + t * 16 + rowsel) * LDSK + ksel];
          bfr[t] = *(bf16x8*)&Bs[(wn * 64 + t * 16 + rowsel) * LDSK + ksel];
        }
#pragma unroll
        for (int mi = 0; mi < 4; ++mi)
#pragma unroll
          for (int nj = 0; nj < 4; ++nj)
            acc[mi][nj] = __builtin_amdgcn_mfma_f32_16x16x32_bf16(
                af[mi], bfr[nj], acc[mi][nj], 0, 0, 0);
      }
      __syncthreads();
    }
    const int crow = (lane >> 4) * 4;
    const int ccol = lane & 15;
#pragma unroll
    for (int nj = 0; nj < 4; ++nj) {
      int gc = n0 + wn * 64 + nj * 16 + ccol;
      float bv = bias[gc];
#pragma unroll
      for (int mi = 0; mi < 4; ++mi) {
        int gr = m0 + wm * 64 + mi * 16 + crow;
#pragma unroll
        for (int r = 0; r < 4; ++r)
          Wh[(size_t)(gr + r) * F + gc] = (_Float16)(acc[mi][nj][r] + bv);
      }
    }
    return;
  }
  if (blockIdx.x < GEMM_BLOCKS + NAB) {
    // ---- binA2 part
    int* h = (int*)smem;
    int* lofs = h + NB;
    int* lcur = lofs + NB;
    int* gb = lcur + NB;
    unsigned* stage = (unsigned*)(gb + NB);  // EPB entries
    const int t = threadIdx.x;
    for (int i = t; i < NB; i += 256) { h[i] = 0; lcur[i] = 0; }
    __syncthreads();
    const int base = (blockIdx.x - GEMM_BLOCKS) * EPB;
    const int cnt = min(EPB, N_EDGES - base);
#pragma unroll
    for (int j = 0; j < 16; ++j) {
      int k = base + j * 256 + t;
      if (k < N_EDGES) atomicAdd(&h[row[k] >> 8], 1);
    }
    __syncthreads();
    if (t == 0) {
      int run = 0;
      for (int i = 0; i < NB; ++i) { lofs[i] = run; run += h[i]; }
    }
    __syncthreads();
    if (t < NB && h[t] > 0) gb[t] = atomicAdd(&gcur[t], h[t]);
    __syncthreads();
#pragma unroll
    for (int j = 0; j < 16; ++j) {
      int k = base + j * 256 + t;
      if (k < N_EDGES) {
        int r = row[k], b = r >> 8;
        int lp = lofs[b] + atomicAdd(&lcur[b], 1);
        stage[lp] = ((unsigned)b << 24) | ((unsigned)(r & 255) << 16) |
                    (unsigned)col[k];
      }
    }
    __syncthreads();
#pragma unroll
    for (int j = 0; j < 16; ++j) {
      int s = j * 256 + t;
      if (s < cnt) {
        unsigned wv = stage[s];
        int b = wv >> 24;
        gstage[(size_t)b * CAP + gb[b] + (s - lofs[b])] = wv & 0x00FFFFFFu;
      }
    }
    return;
  }
  // ---- fvec part: grid-stride fat blocks (4 nodes/iter/block)
  const int lane = threadIdx.x & 63, w = threadIdx.x >> 6;
  const int slot = blockIdx.x - GEMM_BLOCKS - NAB;
  float4 v1 = *(const float4*)(wa + lane * 4);
  float4 v2 = *(const float4*)(wa + F + lane * 4);
  for (int node = slot * 4 + w; node < N_NODES; node += FVEC_SLOTS * 4) {
    float4 xv = *(const float4*)(x + (size_t)node * F + lane * 4);
    float s1 = xv.x * v1.x + xv.y * v1.y + xv.z * v1.z + xv.w * v1.w;
    float s2 = xv.x * v2.x + xv.y * v2.y + xv.z * v2.z + xv.w * v2.w;
#pragma unroll
    for (int off = 32; off > 0; off >>= 1) {
      s1 += __shfl_down(s1, off, 64);
      s2 += __shfl_down(s2, off, 64);
    }
    if (lane == 0) { f_dst[node] = s1; f_row[node] = s2; }
  }
}

// ---- L3: binB (512 thr): per-(row,colbin) histogram -> entries placed
// COL-SORTED within each row (8 bins, q = col>>13). Additionally exports the
// per-(row,bin) absolute start offsets (bstart) so the pull kernel can do a
// globally phase-synchronized bin sweep.
__global__ __launch_bounds__(512) void binB(const int* __restrict__ gcur,
                                            const unsigned* __restrict__ gstage,
                                            const float* __restrict__ f_dst,
                                            const float* __restrict__ f_row,
                                            const float* __restrict__ cb,
                                            int2* __restrict__ rsc,
                                            float* __restrict__ inv_denom,
                                            unsigned* __restrict__ csr,
                                            int* __restrict__ bstart) {
  __shared__ int cnt2[2048];  // per (row, colbin)
  __shared__ int cur2[2048];
  __shared__ int rcnt[256], rbase[256];
  __shared__ float dsum[256];
  const int t = threadIdx.x;
  const int b = blockIdx.x;
  for (int i = t; i < 2048; i += 512) cnt2[i] = 0;
  if (t < 256) dsum[t] = 0.f;
  __syncthreads();
  const int nb = gcur[b];
  const int start = b * CAP;
  const float cbs = cb[0];
  for (int s = t; s < nb; s += 512) {
    unsigned wv = gstage[start + s];
    int key = (((wv >> 16) & 255) << 3) | ((wv & 0xFFFFu) >> 13);
    atomicAdd(&cnt2[key], 1);
  }
  __syncthreads();
  if (t < 256) {
    int tot = 0;
#pragma unroll
    for (int q = 0; q < 8; ++q) tot += cnt2[t * 8 + q];
    rcnt[t] = tot;
  }
  __syncthreads();
  if (t == 0) {
    int run = 0;
    for (int i = 0; i < 256; ++i) { rbase[i] = run; run += rcnt[i]; }
  }
  __syncthreads();
  if (t < 256) {
    int base = start + rbase[t];
    int g = (b << 8) + t;
    if (g < N_NODES) rsc[g] = make_int2(base, rcnt[t]);
    int run = base;
    int bs[8];
#pragma unroll
    for (int q = 0; q < 8; ++q) {
      cur2[t * 8 + q] = run;
      bs[q] = run;
      run += cnt2[t * 8 + q];
    }
    if (g < N_NODES) {
      *(int4*)&bstart[(size_t)g * 8]     = make_int4(bs[0], bs[1], bs[2], bs[3]);
      *(int4*)&bstart[(size_t)g * 8 + 4] = make_int4(bs[4], bs[5], bs[6], bs[7]);
    }
  }
  __syncthreads();
  for (int s = t; s < nb; s += 512) {
    unsigned wv = gstage[start + s];
    int lr = (wv >> 16) & 255;
    int c = wv & 0xFFFF;
    float ev = f_dst[c] + f_row[(b << 8) + lr] + cbs;
    ev = ev > 0.f ? ev : ALPHA * ev;
    float ex = __expf(ev);
    int p = atomicAdd(&cur2[(lr << 3) | (c >> 13)], 1);  // absolute index
    csr[p] = ((unsigned)f2h_bits(ex) << 16) | (unsigned)c;
    atomicAdd(&dsum[lr], ex);
  }
  __syncthreads();
  if (t < 256) {
    int g = (b << 8) + t;
    if (g < N_NODES) inv_denom[g] = (rcnt[t] > 0) ? (1.0f / dsum[t]) : 0.f;
  }
}

// ---- L4: pull, phase-synchronized col-bin sweep, 4-deep MLP edition.
// (Best measured configuration: 96.5 us pull, 264.9 us total.)
__global__ __launch_bounds__(256) void gat_pull(const int2* __restrict__ rsc,
                                                const unsigned* __restrict__ csr,
                                                const float* __restrict__ inv_denom,
                                                const int* __restrict__ bstart,
                                                const _Float16* __restrict__ Wh,
                                                float* __restrict__ out) {
  __shared__ int sb[4 * NPW * 9];  // 4 waves x 7 nodes x (8 starts + row end)
  const int lane = threadIdx.x & 63;
  const int wv_id = threadIdx.x >> 6;
  const int wid = blockIdx.x * 4 + wv_id;
  // cooperative bounds stage: entry e = w*63 + jn*9 + q
  for (int e = threadIdx.x; e < 4 * NPW * 9; e += 256) {
    int w = e / (NPW * 9);
    int rem = e - w * (NPW * 9);
    int jn = rem / 9, q = rem - jn * 9;
    int i = blockIdx.x * 4 + w + jn * NW_TOT;
    int v = 0;
    if (i < N_NODES) {
      if (q < 8) v = bstart[(size_t)i * 8 + q];
      else { int2 rc = rsc[i]; v = rc.x + rc.y; }
    }
    sb[e] = v;
  }
  __syncthreads();
  const int* mb = &sb[wv_id * NPW * 9];
  const char* whb = (const char*)Wh;
  const unsigned chanoff = (unsigned)lane * 8u;  // 4 fp16 channels / lane
  const int l16 = lane & 15;
  float a0[NPW], a1[NPW], a2[NPW], a3[NPW];
#pragma unroll
  for (int jn = 0; jn < NPW; ++jn) a0[jn] = a1[jn] = a2[jn] = a3[jn] = 0.f;
  for (int q = 0; q < NBIN; ++q) {
    // prefetch jn=0 segment csr line
    int pp = mb[q], pe = mb[q + 1];
    unsigned cw0 = 0;
    if (pp + l16 < pe) cw0 = csr[pp + l16];
#pragma unroll
    for (int jn = 0; jn < NPW; ++jn) {
      const int cpp = pp, cpe = pe;
      unsigned cw = cw0;
      if (jn + 1 < NPW) {  // prefetch next node's segment
        pp = mb[(jn + 1) * 9 + q];
        pe = mb[(jn + 1) * 9 + q + 1];
        cw0 = 0;
        if (pp + l16 < pe) cw0 = csr[pp + l16];
      }
      const int len = cpe - cpp;
      for (int done = 0; done < len; done += 16) {
        if (done) {  // chunks beyond the first: reload line (rare, len>16)
          cw = 0;
          if (cpp + done + l16 < cpe) cw = csr[cpp + done + l16];
        }
        int cl = len - done;
        if (cl > 16) cl = 16;
        for (int jb = 0; jb < cl; jb += 4) {
          // 4-edge batch: uniform extracts, clamped to edge 0 when past end
          const int j1 = (jb + 1 < cl) ? jb + 1 : 0;
          const int j2 = (jb + 2 < cl) ? jb + 2 : 0;
          const int j3 = (jb + 3 < cl) ? jb + 3 : 0;
          unsigned w0 = __builtin_amdgcn_readlane(cw, jb);
          unsigned w1 = __builtin_amdgcn_readlane(cw, j1);
          unsigned w2 = __builtin_amdgcn_readlane(cw, j2);
          unsigned w3 = __builtin_amdgcn_readlane(cw, j3);
          half4 v0 = *(const half4*)(whb + (size_t)(w0 & 0xFFFFu) * 512u + chanoff);
          half4 v1 = *(const half4*)(whb + (size_t)(w1 & 0xFFFFu) * 512u + chanoff);
          half4 v2 = *(const half4*)(whb + (size_t)(w2 & 0xFFFFu) * 512u + chanoff);
          half4 v3 = *(const half4*)(whb + (size_t)(w3 & 0xFFFFu) * 512u + chanoff);
          float x0 = h_bits2f((unsigned short)(w0 >> 16));
          float x1 = (jb + 1 < cl) ? h_bits2f((unsigned short)(w1 >> 16)) : 0.f;
          float x2 = (jb + 2 < cl) ? h_bits2f((unsigned short)(w2 >> 16)) : 0.f;
          float x3 = (jb + 3 < cl) ? h_bits2f((unsigned short)(w3 >> 16)) : 0.f;
          a0[jn] += x0 * (float)v0[0]; a1[jn] += x0 * (float)v0[1];
          a2[jn] += x0 * (float)v0[2]; a3[jn] += x0 * (float)v0[3];
          a0[jn] += x1 * (float)v1[0]; a1[jn] += x1 * (float)v1[1];
          a2[jn] += x1 * (float)v1[2]; a3[jn] += x1 * (float)v1[3];
          a0[jn] += x2 * (float)v2[0]; a1[jn] += x2 * (float)v2[1];
          a2[jn] += x2 * (float)v2[2]; a3[jn] += x2 * (float)v2[3];
          a0[jn] += x3 * (float)v3[0]; a1[jn] += x3 * (float)v3[1];
          a2[jn] += x3 * (float)v3[2]; a3[jn] += x3 * (float)v3[3];
        }
      }
    }
  }
  // finalize: scale, relu, store (lane owns its 4 channels directly)
#pragma unroll
  for (int jn = 0; jn < NPW; ++jn) {
    int i = wid + jn * NW_TOT;
    if (i >= N_NODES) continue;
    const float inv = inv_denom[i];
    float4 o = make_float4(fmaxf(a0[jn] * inv, 0.f), fmaxf(a1[jn] * inv, 0.f),
                           fmaxf(a2[jn] * inv, 0.f), fmaxf(a3[jn] * inv, 0.f));
    ((float4*)out)[(size_t)i * 64 + lane] = o;
  }
}

extern "C" void kernel_launch(void* const* d_in, const int* in_sizes, int n_in,
                              void* d_out, int out_size, void* d_ws, size_t ws_size,
                              hipStream_t stream) {
  const float* x   = (const float*)d_in[0];
  const float* W_w = (const float*)d_in[1];
  const float* W_b = (const float*)d_in[2];
  const float* a_w = (const float*)d_in[3];
  const float* a_b = (const float*)d_in[4];
  const int*   row = (const int*)d_in[5];
  const int*   col = (const int*)d_in[6];
  float* out = (float*)d_out;

  float* ws = (float*)d_ws;
  size_t off = 0;
  _Float16* Wh = (_Float16*)(ws + off); off += (size_t)NP * F / 2;       // fp16
  unsigned short* Wt = (unsigned short*)(ws + off); off += (F * F) / 2;  // bf16
  float* wa = ws + off;            off += 2 * F;
  float* cb = ws + off;            off += 8;
  float* f_dst = ws + off;         off += NP;
  float* f_row = ws + off;         off += NP;
  int* gcur = (int*)(ws + off);    off += NB;
  int2* rsc = (int2*)(ws + off);   off += 2 * (size_t)NP;
  float* inv_denom = (float*)(ws + off); off += NP;
  unsigned* gstage = (unsigned*)(ws + off); off += (size_t)NB * CAP;
  unsigned* csr = (unsigned*)(ws + off); off += (size_t)NB * CAP;
  int* bstart = (int*)(ws + off);  off += (size_t)NP * 8;
  (void)ws_size; (void)in_sizes; (void)n_in; (void)out_size;

  hipLaunchKernelGGL(prep_w, dim3(65), dim3(256), 0, stream, W_w, a_w, W_b,
                     a_b, Wt, wa, cb, gcur);
  hipLaunchKernelGGL(gemm_fvec_binA2, dim3(GEMM_BLOCKS + NAB + FVEC_SLOTS),
                     dim3(256), 0, stream, x, Wt, W_b, wa, row, col, Wh,
                     f_dst, f_row, gcur, gstage);
  hipLaunchKernelGGL(binB, dim3(NB), dim3(512), 0, stream, gcur, gstage,
                     f_dst, f_row, cb, rsc, inv_denom, csr, bstart);
  hipLaunchKernelGGL(gat_pull, dim3(PULL_BLOCKS), dim3(256), 0, stream,
                     rsc, csr, inv_denom, bstart, Wh, out);
}

// Round 11
// 261.410 us; speedup vs baseline: 1.0721x; 1.0163x over previous
//
#include <hip/hip_runtime.h>
#include <math.h>

#define N_NODES 50000
#define N_EDGES 1600000
#define F 256
#define ALPHA 0.2f
#define NP 50048   // padded node count (multiple of 128)
#define NB 196     // coarse buckets: bucket = row >> 8 (256 rows each)
#define CAP 10240  // fixed bucket capacity (Poisson mean 8192, sigma 91 -> 22σ)
#define EPB 4096   // edges per binning block
#define NAB ((N_EDGES + EPB - 1) / EPB)  // 391
#define GEMM_BLOCKS 782  // (NP/128) * (F/128)
#define FVEC_SLOTS 2048  // grid-stride fat blocks for the projection part
#define PULL_BLOCKS 2048 // persistent pull blocks (8 per CU)
#define NW_TOT (PULL_BLOCKS * 4)  // 8192 persistent waves
#define NPW 7    // nodes per wave (ceil(50000/8192))
#define NBIN 8   // col bins (col >> 13), 3.2 MB Wh slice per bin

typedef short bf16x8 __attribute__((ext_vector_type(8)));
typedef float f32x4 __attribute__((ext_vector_type(4)));
typedef _Float16 half4 __attribute__((ext_vector_type(4)));
typedef _Float16 half8 __attribute__((ext_vector_type(8)));

__device__ __forceinline__ unsigned short f2bf(float f) {
  union { float f; unsigned u; } v; v.f = f;
  unsigned u = v.u;
  return (unsigned short)((u + 0x7fffu + ((u >> 16) & 1u)) >> 16);
}

__device__ __forceinline__ unsigned short f2h_bits(float f) {
  union { _Float16 h; unsigned short u; } v;
  v.h = (_Float16)f;
  return v.u;
}

__device__ __forceinline__ float h_bits2f(unsigned short u) {
  union { _Float16 h; unsigned short u; } v;
  v.u = u;
  return (float)v.h;
}

// ---- L1: prep_w: W -> Wt bf16 transposed; wa = W @ a_halves; cb; zero gcur
__global__ __launch_bounds__(256) void prep_w(const float* __restrict__ W,
                                              const float* __restrict__ a_w,
                                              const float* __restrict__ W_b,
                                              const float* __restrict__ a_b,
                                              unsigned short* __restrict__ Wt,
                                              float* __restrict__ wa,
                                              float* __restrict__ cb,
                                              int* __restrict__ gcur) {
  if (blockIdx.x == 64) {  // zero the bucket cursors (replaces memset launch)
    if (threadIdx.x < NB) gcur[threadIdx.x] = 0;
    return;
  }
  const int lane = threadIdx.x & 63, w = threadIdx.x >> 6;
  const int k = blockIdx.x * 4 + w;  // 0..255
  float4 wv = *(const float4*)(W + (size_t)k * F + lane * 4);
  float4 a1 = *(const float4*)(a_w + lane * 4);
  float4 a2 = *(const float4*)(a_w + F + lane * 4);
  Wt[(size_t)(lane * 4 + 0) * F + k] = f2bf(wv.x);
  Wt[(size_t)(lane * 4 + 1) * F + k] = f2bf(wv.y);
  Wt[(size_t)(lane * 4 + 2) * F + k] = f2bf(wv.z);
  Wt[(size_t)(lane * 4 + 3) * F + k] = f2bf(wv.w);
  float s1 = wv.x * a1.x + wv.y * a1.y + wv.z * a1.z + wv.w * a1.w;
  float s2 = wv.x * a2.x + wv.y * a2.y + wv.z * a2.z + wv.w * a2.w;
#pragma unroll
  for (int off = 32; off > 0; off >>= 1) {
    s1 += __shfl_down(s1, off, 64);
    s2 += __shfl_down(s2, off, 64);
  }
  if (lane == 0) { wa[k] = s1; wa[F + k] = s2; }
  if (blockIdx.x == 0 && w == 0) {
    float4 b = *(const float4*)(W_b + lane * 4);
    float t1 = b.x * (a1.x + a2.x) + b.y * (a1.y + a2.y) +
               b.z * (a1.z + a2.z) + b.w * (a1.w + a2.w);
#pragma unroll
    for (int off = 32; off > 0; off >>= 1) t1 += __shfl_down(t1, off, 64);
    if (lane == 0) cb[0] = t1 + a_b[0];
  }
}

// ---- L2: fused GEMM [0,782) + binA2 [782,1173) + fvec [1173,1173+2048)
#define LDSK 72
__global__ __launch_bounds__(256) void gemm_fvec_binA2(
    const float* __restrict__ x,
    const unsigned short* __restrict__ Wt,
    const float* __restrict__ bias,
    const float* __restrict__ wa,
    const int* __restrict__ row,
    const int* __restrict__ col,
    _Float16* __restrict__ Wh,
    float* __restrict__ f_dst,
    float* __restrict__ f_row,
    int* __restrict__ gcur,
    unsigned* __restrict__ gstage) {
  __shared__ char smem[2 * 128 * LDSK * 2];  // 36864 B arena
  if (blockIdx.x < GEMM_BLOCKS) {
    // ---- GEMM part: Wh(fp16) = bf16(x) @ Wt^T + bias
    short* As = (short*)smem;
    short* Bs = As + 128 * LDSK;
    const int tid = threadIdx.x;
    const int lane = tid & 63;
    const int w = tid >> 6;
    const int wm = w >> 1, wn = w & 1;
    const int m0 = (blockIdx.x >> 1) * 128;
    const int n0 = (blockIdx.x & 1) * 128;
    f32x4 acc[4][4] = {{{0.f, 0.f, 0.f, 0.f}}};
    const int srow = tid >> 3;   // 0..31
    const int schunk = tid & 7;  // 0..7
    for (int k0 = 0; k0 < F; k0 += 64) {
#pragma unroll
      for (int i = 0; i < 4; ++i) {
        int r = i * 32 + srow;
        int gm = m0 + r; if (gm > N_NODES - 1) gm = N_NODES - 1;
        const float* src = x + (size_t)gm * F + k0 + schunk * 8;
        float4 lo = *(const float4*)src;
        float4 hi = *(const float4*)(src + 4);
        bf16x8 v;
        v[0] = (short)f2bf(lo.x); v[1] = (short)f2bf(lo.y);
        v[2] = (short)f2bf(lo.z); v[3] = (short)f2bf(lo.w);
        v[4] = (short)f2bf(hi.x); v[5] = (short)f2bf(hi.y);
        v[6] = (short)f2bf(hi.z); v[7] = (short)f2bf(hi.w);
        *(bf16x8*)&As[r * LDSK + schunk * 8] = v;
        *(bf16x8*)&Bs[r * LDSK + schunk * 8] =
            *(const bf16x8*)(Wt + (size_t)(n0 + r) * F + k0 + schunk * 8);
      }
      __syncthreads();
#pragma unroll
      for (int kk = 0; kk < 64; kk += 32) {
        const int rowsel = lane & 15;
        const int ksel = kk + (lane >> 4) * 8;
        bf16x8 af[4], bfr[4];
#pragma unroll
        for (int t = 0; t < 4; ++t) {
          af[t] = *(bf16x8*)&As[(wm * 64 + t * 16 + rowsel) * LDSK + ksel];
          bfr[t] = *(bf16x8*)&Bs[(wn * 64 + t * 16 + rowsel) * LDSK + ksel];
        }
#pragma unroll
        for (int mi = 0; mi < 4; ++mi)
#pragma unroll
          for (int nj = 0; nj < 4; ++nj)
            acc[mi][nj] = __builtin_amdgcn_mfma_f32_16x16x32_bf16(
                af[mi], bfr[nj], acc[mi][nj], 0, 0, 0);
      }
      __syncthreads();
    }
    const int crow = (lane >> 4) * 4;
    const int ccol = lane & 15;
#pragma unroll
    for (int nj = 0; nj < 4; ++nj) {
      int gc = n0 + wn * 64 + nj * 16 + ccol;
      float bv = bias[gc];
#pragma unroll
      for (int mi = 0; mi < 4; ++mi) {
        int gr = m0 + wm * 64 + mi * 16 + crow;
#pragma unroll
        for (int r = 0; r < 4; ++r)
          Wh[(size_t)(gr + r) * F + gc] = (_Float16)(acc[mi][nj][r] + bv);
      }
    }
    return;
  }
  if (blockIdx.x < GEMM_BLOCKS + NAB) {
    // ---- binA2 part
    int* h = (int*)smem;
    int* lofs = h + NB;
    int* lcur = lofs + NB;
    int* gb = lcur + NB;
    unsigned* stage = (unsigned*)(gb + NB);  // EPB entries
    const int t = threadIdx.x;
    for (int i = t; i < NB; i += 256) { h[i] = 0; lcur[i] = 0; }
    __syncthreads();
    const int base = (blockIdx.x - GEMM_BLOCKS) * EPB;
    const int cnt = min(EPB, N_EDGES - base);
#pragma unroll
    for (int j = 0; j < 16; ++j) {
      int k = base + j * 256 + t;
      if (k < N_EDGES) atomicAdd(&h[row[k] >> 8], 1);
    }
    __syncthreads();
    if (t == 0) {
      int run = 0;
      for (int i = 0; i < NB; ++i) { lofs[i] = run; run += h[i]; }
    }
    __syncthreads();
    if (t < NB && h[t] > 0) gb[t] = atomicAdd(&gcur[t], h[t]);
    __syncthreads();
#pragma unroll
    for (int j = 0; j < 16; ++j) {
      int k = base + j * 256 + t;
      if (k < N_EDGES) {
        int r = row[k], b = r >> 8;
        int lp = lofs[b] + atomicAdd(&lcur[b], 1);
        stage[lp] = ((unsigned)b << 24) | ((unsigned)(r & 255) << 16) |
                    (unsigned)col[k];
      }
    }
    __syncthreads();
#pragma unroll
    for (int j = 0; j < 16; ++j) {
      int s = j * 256 + t;
      if (s < cnt) {
        unsigned wv = stage[s];
        int b = wv >> 24;
        gstage[(size_t)b * CAP + gb[b] + (s - lofs[b])] = wv & 0x00FFFFFFu;
      }
    }
    return;
  }
  // ---- fvec part: grid-stride fat blocks (4 nodes/iter/block)
  const int lane = threadIdx.x & 63, w = threadIdx.x >> 6;
  const int slot = blockIdx.x - GEMM_BLOCKS - NAB;
  float4 v1 = *(const float4*)(wa + lane * 4);
  float4 v2 = *(const float4*)(wa + F + lane * 4);
  for (int node = slot * 4 + w; node < N_NODES; node += FVEC_SLOTS * 4) {
    float4 xv = *(const float4*)(x + (size_t)node * F + lane * 4);
    float s1 = xv.x * v1.x + xv.y * v1.y + xv.z * v1.z + xv.w * v1.w;
    float s2 = xv.x * v2.x + xv.y * v2.y + xv.z * v2.z + xv.w * v2.w;
#pragma unroll
    for (int off = 32; off > 0; off >>= 1) {
      s1 += __shfl_down(s1, off, 64);
      s2 += __shfl_down(s2, off, 64);
    }
    if (lane == 0) { f_dst[node] = s1; f_row[node] = s2; }
  }
}

// ---- L3: binB (512 thr): per-(row,colbin) histogram -> entries placed
// COL-SORTED within each row (8 bins, q = col>>13). Additionally exports the
// per-(row,bin) absolute start offsets (bstart) so the pull kernel can do a
// globally phase-synchronized bin sweep.
__global__ __launch_bounds__(512) void binB(const int* __restrict__ gcur,
                                            const unsigned* __restrict__ gstage,
                                            const float* __restrict__ f_dst,
                                            const float* __restrict__ f_row,
                                            const float* __restrict__ cb,
                                            int2* __restrict__ rsc,
                                            float* __restrict__ inv_denom,
                                            unsigned* __restrict__ csr,
                                            int* __restrict__ bstart) {
  __shared__ int cnt2[2048];  // per (row, colbin)
  __shared__ int cur2[2048];
  __shared__ int rcnt[256], rbase[256];
  __shared__ float dsum[256];
  const int t = threadIdx.x;
  const int b = blockIdx.x;
  for (int i = t; i < 2048; i += 512) cnt2[i] = 0;
  if (t < 256) dsum[t] = 0.f;
  __syncthreads();
  const int nb = gcur[b];
  const int start = b * CAP;
  const float cbs = cb[0];
  for (int s = t; s < nb; s += 512) {
    unsigned wv = gstage[start + s];
    int key = (((wv >> 16) & 255) << 3) | ((wv & 0xFFFFu) >> 13);
    atomicAdd(&cnt2[key], 1);
  }
  __syncthreads();
  if (t < 256) {
    int tot = 0;
#pragma unroll
    for (int q = 0; q < 8; ++q) tot += cnt2[t * 8 + q];
    rcnt[t] = tot;
  }
  __syncthreads();
  if (t == 0) {
    int run = 0;
    for (int i = 0; i < 256; ++i) { rbase[i] = run; run += rcnt[i]; }
  }
  __syncthreads();
  if (t < 256) {
    int base = start + rbase[t];
    int g = (b << 8) + t;
    if (g < N_NODES) rsc[g] = make_int2(base, rcnt[t]);
    int run = base;
    int bs[8];
#pragma unroll
    for (int q = 0; q < 8; ++q) {
      cur2[t * 8 + q] = run;
      bs[q] = run;
      run += cnt2[t * 8 + q];
    }
    if (g < N_NODES) {
      *(int4*)&bstart[(size_t)g * 8]     = make_int4(bs[0], bs[1], bs[2], bs[3]);
      *(int4*)&bstart[(size_t)g * 8 + 4] = make_int4(bs[4], bs[5], bs[6], bs[7]);
    }
  }
  __syncthreads();
  for (int s = t; s < nb; s += 512) {
    unsigned wv = gstage[start + s];
    int lr = (wv >> 16) & 255;
    int c = wv & 0xFFFF;
    float ev = f_dst[c] + f_row[(b << 8) + lr] + cbs;
    ev = ev > 0.f ? ev : ALPHA * ev;
    float ex = __expf(ev);
    int p = atomicAdd(&cur2[(lr << 3) | (c >> 13)], 1);  // absolute index
    csr[p] = ((unsigned)f2h_bits(ex) << 16) | (unsigned)c;
    atomicAdd(&dsum[lr], ex);
  }
  __syncthreads();
  if (t < 256) {
    int g = (b << 8) + t;
    if (g < N_NODES) inv_denom[g] = (rcnt[t] > 0) ? (1.0f / dsum[t]) : 0.f;
  }
}

// ---- L4: pull, phase-synchronized col-bin sweep, 4-deep MLP,
// SCALARIZED bounds edition: every wave-uniform value (segment bounds,
// loop counters, csr words, Wh base offsets, weights) is explicitly
// hoisted to SGPRs via readfirstlane/readlane, so loop control, clamps
// and addressing run on the SALU. VALU work per edge drops to
// ~1 cvt + 4 FMA. Traffic/MLP structure identical to the proven r5 point.
__global__ __launch_bounds__(256) void gat_pull(const int2* __restrict__ rsc,
                                                const unsigned* __restrict__ csr,
                                                const float* __restrict__ inv_denom,
                                                const int* __restrict__ bstart,
                                                const _Float16* __restrict__ Wh,
                                                float* __restrict__ out) {
  __shared__ int sb[4 * NPW * 9];  // 4 waves x 7 nodes x (8 starts + row end)
  const int lane = threadIdx.x & 63;
  const int wv_id = threadIdx.x >> 6;
  const int wid = blockIdx.x * 4 + wv_id;
  // cooperative bounds stage: entry e = w*63 + jn*9 + q
  for (int e = threadIdx.x; e < 4 * NPW * 9; e += 256) {
    int w = e / (NPW * 9);
    int rem = e - w * (NPW * 9);
    int jn = rem / 9, q = rem - jn * 9;
    int i = blockIdx.x * 4 + w + jn * NW_TOT;
    int v = 0;
    if (i < N_NODES) {
      if (q < 8) v = bstart[(size_t)i * 8 + q];
      else { int2 rc = rsc[i]; v = rc.x + rc.y; }
    }
    sb[e] = v;
  }
  __syncthreads();
  const int* mb = &sb[wv_id * NPW * 9];
  const char* whb = (const char*)Wh;
  const unsigned chanoff = (unsigned)lane * 8u;  // 4 fp16 channels / lane
  const int l16 = lane & 15;
  float a0[NPW], a1[NPW], a2[NPW], a3[NPW];
#pragma unroll
  for (int jn = 0; jn < NPW; ++jn) a0[jn] = a1[jn] = a2[jn] = a3[jn] = 0.f;
  for (int q = 0; q < NBIN; ++q) {
    // prefetch jn=0 segment csr line; bounds hoisted to SGPR
    int pp = __builtin_amdgcn_readfirstlane(mb[q]);
    int pe = __builtin_amdgcn_readfirstlane(mb[q + 1]);
    unsigned cw0 = 0;
    if (pp + l16 < pe) cw0 = csr[pp + l16];
#pragma unroll
    for (int jn = 0; jn < NPW; ++jn) {
      const int cpp = pp, cpe = pe;
      unsigned cw = cw0;
      if (jn + 1 < NPW) {  // prefetch next node's segment (SGPR bounds)
        pp = __builtin_amdgcn_readfirstlane(mb[(jn + 1) * 9 + q]);
        pe = __builtin_amdgcn_readfirstlane(mb[(jn + 1) * 9 + q + 1]);
        cw0 = 0;
        if (pp + l16 < pe) cw0 = csr[pp + l16];
      }
      const int len = cpe - cpp;  // SGPR
      for (int done = 0; done < len; done += 16) {
        if (done) {  // chunks beyond the first: reload line (rare, len>16)
          cw = 0;
          if (cpp + done + l16 < cpe) cw = csr[cpp + done + l16];
        }
        int cl = len - done;      // SGPR
        if (cl > 16) cl = 16;
        for (int jb = 0; jb < cl; jb += 4) {  // SGPR loop, scalar branch
          // 4-edge batch: scalar extracts/selects, clamped to edge 0
          const int j1 = (jb + 1 < cl) ? jb + 1 : 0;  // s_cselect
          const int j2 = (jb + 2 < cl) ? jb + 2 : 0;
          const int j3 = (jb + 3 < cl) ? jb + 3 : 0;
          unsigned w0 = __builtin_amdgcn_readlane(cw, jb);  // SGPR
          unsigned w1 = __builtin_amdgcn_readlane(cw, j1);
          unsigned w2 = __builtin_amdgcn_readlane(cw, j2);
          unsigned w3 = __builtin_amdgcn_readlane(cw, j3);
          // scalar byte offsets into Wh; per-lane part is loop-invariant
          unsigned o0 = (w0 & 0xFFFFu) << 9;  // s_and + s_lshl
          unsigned o1 = (w1 & 0xFFFFu) << 9;
          unsigned o2 = (w2 & 0xFFFFu) << 9;
          unsigned o3 = (w3 & 0xFFFFu) << 9;
          half4 v0 = *(const half4*)(whb + o0 + chanoff);
          half4 v1 = *(const half4*)(whb + o1 + chanoff);
          half4 v2 = *(const half4*)(whb + o2 + chanoff);
          half4 v3 = *(const half4*)(whb + o3 + chanoff);
          // fp16 weights from scalar hi16; pads zeroed via scalar select
          unsigned h0 = w0 >> 16;                       // s_lshr
          unsigned h1 = (jb + 1 < cl) ? (w1 >> 16) : 0u;
          unsigned h2 = (jb + 2 < cl) ? (w2 >> 16) : 0u;
          unsigned h3 = (jb + 3 < cl) ? (w3 >> 16) : 0u;
          float x0 = h_bits2f((unsigned short)h0);
          float x1 = h_bits2f((unsigned short)h1);
          float x2 = h_bits2f((unsigned short)h2);
          float x3 = h_bits2f((unsigned short)h3);
          a0[jn] += x0 * (float)v0[0]; a1[jn] += x0 * (float)v0[1];
          a2[jn] += x0 * (float)v0[2]; a3[jn] += x0 * (float)v0[3];
          a0[jn] += x1 * (float)v1[0]; a1[jn] += x1 * (float)v1[1];
          a2[jn] += x1 * (float)v1[2]; a3[jn] += x1 * (float)v1[3];
          a0[jn] += x2 * (float)v2[0]; a1[jn] += x2 * (float)v2[1];
          a2[jn] += x2 * (float)v2[2]; a3[jn] += x2 * (float)v2[3];
          a0[jn] += x3 * (float)v3[0]; a1[jn] += x3 * (float)v3[1];
          a2[jn] += x3 * (float)v3[2]; a3[jn] += x3 * (float)v3[3];
        }
      }
    }
  }
  // finalize: scale, relu, store (lane owns its 4 channels directly)
#pragma unroll
  for (int jn = 0; jn < NPW; ++jn) {
    int i = wid + jn * NW_TOT;
    if (i >= N_NODES) continue;
    const float inv = inv_denom[i];
    float4 o = make_float4(fmaxf(a0[jn] * inv, 0.f), fmaxf(a1[jn] * inv, 0.f),
                           fmaxf(a2[jn] * inv, 0.f), fmaxf(a3[jn] * inv, 0.f));
    ((float4*)out)[(size_t)i * 64 + lane] = o;
  }
}

extern "C" void kernel_launch(void* const* d_in, const int* in_sizes, int n_in,
                              void* d_out, int out_size, void* d_ws, size_t ws_size,
                              hipStream_t stream) {
  const float* x   = (const float*)d_in[0];
  const float* W_w = (const float*)d_in[1];
  const float* W_b = (const float*)d_in[2];
  const float* a_w = (const float*)d_in[3];
  const float* a_b = (const float*)d_in[4];
  const int*   row = (const int*)d_in[5];
  const int*   col = (const int*)d_in[6];
  float* out = (float*)d_out;

  float* ws = (float*)d_ws;
  size_t off = 0;
  _Float16* Wh = (_Float16*)(ws + off); off += (size_t)NP * F / 2;       // fp16
  unsigned short* Wt = (unsigned short*)(ws + off); off += (F * F) / 2;  // bf16
  float* wa = ws + off;            off += 2 * F;
  float* cb = ws + off;            off += 8;
  float* f_dst = ws + off;         off += NP;
  float* f_row = ws + off;         off += NP;
  int* gcur = (int*)(ws + off);    off += NB;
  int2* rsc = (int2*)(ws + off);   off += 2 * (size_t)NP;
  float* inv_denom = (float*)(ws + off); off += NP;
  unsigned* gstage = (unsigned*)(ws + off); off += (size_t)NB * CAP;
  unsigned* csr = (unsigned*)(ws + off); off += (size_t)NB * CAP;
  int* bstart = (int*)(ws + off);  off += (size_t)NP * 8;
  (void)ws_size; (void)in_sizes; (void)n_in; (void)out_size;

  hipLaunchKernelGGL(prep_w, dim3(65), dim3(256), 0, stream, W_w, a_w, W_b,
                     a_b, Wt, wa, cb, gcur);
  hipLaunchKernelGGL(gemm_fvec_binA2, dim3(GEMM_BLOCKS + NAB + FVEC_SLOTS),
                     dim3(256), 0, stream, x, Wt, W_b, wa, row, col, Wh,
                     f_dst, f_row, gcur, gstage);
  hipLaunchKernelGGL(binB, dim3(NB), dim3(512), 0, stream, gcur, gstage,
                     f_dst, f_row, cb, rsc, inv_denom, csr, bstart);
  hipLaunchKernelGGL(gat_pull, dim3(PULL_BLOCKS), dim3(256), 0, stream,
                     rsc, csr, inv_denom, bstart, Wh, out);
}